// Round 4
// baseline (728.680 us; speedup 1.0000x reference)
//
#include <hip/hip_runtime.h>
#include <hip/hip_bf16.h>

#define DIM 64
#define BROWS 256                 // destination rows per bucket
#define COLBITS 17                // col index bits in packed edge (nNodes <= 131072)
#define COLMASK ((1 << COLBITS) - 1)
#define MAXB 512                  // max buckets supported by scan / LDS hist

typedef __attribute__((ext_vector_type(8))) short bf16x8;  // 8 bf16 = 4 VGPRs
typedef __attribute__((ext_vector_type(4))) float f32x4;

static __device__ __forceinline__ short f2bs(float f) {
  __hip_bfloat16 h = __float2bfloat16(f);
  return *reinterpret_cast<const short*>(&h);
}

// ---------------------------------------------------------------------------
// A) Bucket histogram: bucket = row >> 8. Per-WG LDS hist, one global atomic
//    per (WG,bucket). 4096 edges per 256-thread WG, coalesced int4 loads.
// ---------------------------------------------------------------------------
__global__ __launch_bounds__(256) void bucket_hist_kernel(
    const int* __restrict__ ei, int* __restrict__ bhist, int nEdges, int nB) {
  __shared__ int h[MAXB];
  for (int i = threadIdx.x; i < nB; i += 256) h[i] = 0;
  __syncthreads();
  const int blkBase = blockIdx.x * 4096;
#pragma unroll
  for (int j = 0; j < 4; ++j) {
    int i = blkBase + j * 1024 + threadIdx.x * 4;
    if (i + 4 <= nEdges) {
      int4 r = *(const int4*)(ei + i);
      atomicAdd(&h[r.x >> 8], 1);
      atomicAdd(&h[r.y >> 8], 1);
      atomicAdd(&h[r.z >> 8], 1);
      atomicAdd(&h[r.w >> 8], 1);
    } else {
      int lim = (nEdges < i + 4) ? nEdges : i + 4;
      for (int k = i; k < lim; ++k) atomicAdd(&h[ei[k] >> 8], 1);
    }
  }
  __syncthreads();
  for (int i = threadIdx.x; i < nB; i += 256) {
    int c = h[i];
    if (c) atomicAdd(&bhist[i], c);
  }
}

// ---------------------------------------------------------------------------
// B) Exclusive scan of bucket counts (single 512-thread WG, nB <= 512).
//    boff[nB] = nEdges sentinel; bcur = running global cursors for partition.
// ---------------------------------------------------------------------------
__global__ __launch_bounds__(MAXB) void bucket_scan_kernel(
    const int* __restrict__ bhist, int* __restrict__ boff,
    int* __restrict__ bcur, int nB, int nEdges) {
  __shared__ int s[MAXB];
  int t = threadIdx.x;
  int v = (t < nB) ? bhist[t] : 0;
  s[t] = v;
  __syncthreads();
  for (int off = 1; off < MAXB; off <<= 1) {
    int a = (t >= off) ? s[t - off] : 0;
    __syncthreads();
    s[t] += a;
    __syncthreads();
  }
  if (t < nB) {
    int ex = s[t] - v;
    boff[t] = ex;
    bcur[t] = ex;
  }
  if (t == 0) boff[nB] = nEdges;
}

// ---------------------------------------------------------------------------
// C) Partition edges into bucket-contiguous packed ints:
//    packed = (localRow << 17) | col.
//    Per-WG: LDS count -> reserve global base per bucket -> LDS cursors for
//    local positions. Per-bucket runs of ~10 ints per WG -> line-level
//    locality (write amplification ~2x instead of 16x).
// ---------------------------------------------------------------------------
__global__ __launch_bounds__(1024) void partition_kernel(
    const int* __restrict__ ei, int* __restrict__ bcur,
    int* __restrict__ packed, int nEdges, int nB) {
  __shared__ int h[MAXB];
  __shared__ int base[MAXB];
  const int t = threadIdx.x;
  for (int i = t; i < nB; i += 1024) h[i] = 0;
  __syncthreads();
  const int i0 = blockIdx.x * 4096 + t * 4;
  int4 r;
  const bool full = (i0 + 4 <= nEdges);
  if (full) {
    r = *(const int4*)(ei + i0);
    atomicAdd(&h[r.x >> 8], 1);
    atomicAdd(&h[r.y >> 8], 1);
    atomicAdd(&h[r.z >> 8], 1);
    atomicAdd(&h[r.w >> 8], 1);
  } else if (i0 < nEdges) {
    for (int k = i0; k < nEdges; ++k) atomicAdd(&h[ei[k] >> 8], 1);
  }
  __syncthreads();
  for (int i = t; i < nB; i += 1024) {
    int c = h[i];
    base[i] = c ? atomicAdd(&bcur[i], c) : 0;
  }
  __syncthreads();
  for (int i = t; i < nB; i += 1024) h[i] = 0;
  __syncthreads();
  if (full) {
    int4 c4 = *(const int4*)(ei + nEdges + i0);
    int b0 = r.x >> 8, b1 = r.y >> 8, b2 = r.z >> 8, b3 = r.w >> 8;
    int p0 = base[b0] + atomicAdd(&h[b0], 1);
    int p1 = base[b1] + atomicAdd(&h[b1], 1);
    int p2 = base[b2] + atomicAdd(&h[b2], 1);
    int p3 = base[b3] + atomicAdd(&h[b3], 1);
    packed[p0] = ((r.x & (BROWS - 1)) << COLBITS) | c4.x;
    packed[p1] = ((r.y & (BROWS - 1)) << COLBITS) | c4.y;
    packed[p2] = ((r.z & (BROWS - 1)) << COLBITS) | c4.z;
    packed[p3] = ((r.w & (BROWS - 1)) << COLBITS) | c4.w;
  } else if (i0 < nEdges) {
    for (int k = i0; k < nEdges; ++k) {
      int row = ei[k], col = ei[nEdges + k];
      int b = row >> 8;
      int p = base[b] + atomicAdd(&h[b], 1);
      packed[p] = ((row & (BROWS - 1)) << COLBITS) | col;
    }
  }
}

// ---------------------------------------------------------------------------
// D) W (f32 row-major [64][64]) -> bf16, same layout.
// ---------------------------------------------------------------------------
__global__ __launch_bounds__(256) void wprep_kernel(
    const float* __restrict__ W, __hip_bfloat16* __restrict__ Wbf) {
  int i = blockIdx.x * 256 + threadIdx.x;
  if (i < DIM * DIM) Wbf[i] = __float2bfloat16(W[i]);
}

// ---------------------------------------------------------------------------
// E) Fused per-bucket scatter-accumulate (LDS f32 atomics) + MFMA linear +
//    bias + relu.  One 1024-thread WG (16 waves) per bucket of 256 rows.
//
//    LDS accumulator [256][64] f32 = 64 KiB, 16B-chunk XOR-swizzled:
//      float idx(row,d) = row*64 + ((d>>2) ^ (row&15))*4 + (d&3)
//    - ds_add (64 lanes, same row, d=lane): chunk perm -> all 32 banks 2-way,
//      conflict-free.
//    - MFMA A-frag ds_read_b128: 64 lanes read chunk (base^r) of rows rb+r;
//      every chunk hit exactly 4x, every bank 8 dwords -> minimum cycles.
//
//    Edge phase: wave w takes a contiguous 1/16 slice of the bucket's packed
//    edges, 8 in flight (broadcast packed load -> coalesced 256B x row load
//    -> fire-and-forget ds_add_f32).
//
//    MFMA phase: wave w owns rows [w*16, w*16+16): read A-frags from LDS,
//    cvt f32->bf16, 8x mfma_f32_16x16x32_bf16 against Wbf (global, L1-hot),
//    add bias, relu, store out (same verified layout as round-3 gemm).
// ---------------------------------------------------------------------------
__global__ __launch_bounds__(1024) void aggregate_gemm_kernel(
    const float* __restrict__ x, const int* __restrict__ packed,
    const int* __restrict__ boff, const __hip_bfloat16* __restrict__ Wbf,
    const float* __restrict__ bias, float* __restrict__ out, int nNodes) {
  __shared__ float accum[BROWS * DIM];  // 65536 B
  const int t = threadIdx.x;
  f32x4* acc4 = (f32x4*)accum;
  for (int i = t; i < BROWS * DIM / 4; i += 1024) acc4[i] = f32x4{0.f, 0.f, 0.f, 0.f};
  __syncthreads();

  const int bkt = blockIdx.x;
  const int es = boff[bkt], ee = boff[bkt + 1];
  const int w = t >> 6, lane = t & 63;
  const int cnt = ee - es;
  const int per = (cnt + 15) >> 4;
  int i = es + w * per;
  int iend = i + per;
  if (iend > ee) iend = ee;

  const int sc = lane >> 2;   // this lane's dim-chunk (pre-swizzle)
  const int di = lane & 3;    // dword within chunk
  const float* xl = x + lane;

#define DSADD(P, V)                                                        \
  {                                                                        \
    int lr_ = (P) >> COLBITS;                                              \
    atomicAdd(&accum[lr_ * DIM + ((sc ^ (lr_ & 15)) << 2) + di], (V));     \
  }

  for (; i + 8 <= iend; i += 8) {
    int p0 = packed[i + 0], p1 = packed[i + 1], p2 = packed[i + 2], p3 = packed[i + 3];
    int p4 = packed[i + 4], p5 = packed[i + 5], p6 = packed[i + 6], p7 = packed[i + 7];
    float v0 = xl[(p0 & COLMASK) << 6];
    float v1 = xl[(p1 & COLMASK) << 6];
    float v2 = xl[(p2 & COLMASK) << 6];
    float v3 = xl[(p3 & COLMASK) << 6];
    float v4 = xl[(p4 & COLMASK) << 6];
    float v5 = xl[(p5 & COLMASK) << 6];
    float v6 = xl[(p6 & COLMASK) << 6];
    float v7 = xl[(p7 & COLMASK) << 6];
    DSADD(p0, v0); DSADD(p1, v1); DSADD(p2, v2); DSADD(p3, v3);
    DSADD(p4, v4); DSADD(p5, v5); DSADD(p6, v6); DSADD(p7, v7);
  }
  for (; i < iend; ++i) {
    int p = packed[i];
    float v = xl[(p & COLMASK) << 6];
    DSADD(p, v);
  }
#undef DSADD
  __syncthreads();

  // --- MFMA phase: wave w -> rows [w*16, w*16+16) ---
  const int r = lane & 15, kg = lane >> 4;
  const int rowf = (w * 16 + r) * 16;  // f32x4 index base of this row
  f32x4 fa0 = acc4[rowf + ((2 * kg) ^ r)];          // dims kg*8 .. +3
  f32x4 fa1 = acc4[rowf + ((2 * kg + 1) ^ r)];      // dims kg*8+4 .. +7
  f32x4 fb0 = acc4[rowf + ((8 + 2 * kg) ^ r)];      // dims 32+kg*8 .. +3
  f32x4 fb1 = acc4[rowf + ((8 + 2 * kg + 1) ^ r)];  // dims 32+kg*8+4 .. +7

  bf16x8 A0, A1;
  A0[0] = f2bs(fa0[0]); A0[1] = f2bs(fa0[1]); A0[2] = f2bs(fa0[2]); A0[3] = f2bs(fa0[3]);
  A0[4] = f2bs(fa1[0]); A0[5] = f2bs(fa1[1]); A0[6] = f2bs(fa1[2]); A0[7] = f2bs(fa1[3]);
  A1[0] = f2bs(fb0[0]); A1[1] = f2bs(fb0[1]); A1[2] = f2bs(fb0[2]); A1[3] = f2bs(fb0[3]);
  A1[4] = f2bs(fb1[0]); A1[5] = f2bs(fb1[1]); A1[6] = f2bs(fb1[2]); A1[7] = f2bs(fb1[3]);

  f32x4 acc[4] = {f32x4{0, 0, 0, 0}, f32x4{0, 0, 0, 0}, f32x4{0, 0, 0, 0}, f32x4{0, 0, 0, 0}};
#pragma unroll
  for (int jt = 0; jt < 4; ++jt) {
    const ushort* bRow = (const ushort*)Wbf + (jt * 16 + r) * DIM + kg * 8;
    bf16x8 B0 = *(const bf16x8*)(bRow);
    bf16x8 B1 = *(const bf16x8*)(bRow + 32);
    acc[jt] = __builtin_amdgcn_mfma_f32_16x16x32_bf16(A0, B0, acc[jt], 0, 0, 0);
    acc[jt] = __builtin_amdgcn_mfma_f32_16x16x32_bf16(A1, B1, acc[jt], 0, 0, 0);
  }

  const int nodeBase = bkt * BROWS + w * 16;
#pragma unroll
  for (int jt = 0; jt < 4; ++jt) {
    int j = jt * 16 + r;
    float bj = bias[j];
#pragma unroll
    for (int q = 0; q < 4; ++q) {
      int node = nodeBase + kg * 4 + q;
      if (node < nNodes) out[(size_t)node * DIM + j] = fmaxf(acc[jt][q] + bj, 0.f);
    }
  }
}

// ---------------------------------------------------------------------------
// Fallback (nNodes > 131072 or tiny ws): round-1 direct atomic scatter +
// in-place linear.
// ---------------------------------------------------------------------------
__global__ __launch_bounds__(256) void scatter_add_kernel(
    const float* __restrict__ x, const int* __restrict__ ei,
    float* __restrict__ aggr, int nEdges) {
  const int lane = threadIdx.x & 63;
  const int e = blockIdx.x * 4 + (threadIdx.x >> 6);
  if (e >= nEdges) return;
  const int row = ei[e];
  const int col = ei[nEdges + e];
  atomicAdd(&aggr[(size_t)row * DIM + lane], x[(size_t)col * DIM + lane]);
}

__global__ __launch_bounds__(256) void linear_relu_inplace_kernel(
    float* __restrict__ io, const float* __restrict__ W,
    const float* __restrict__ b, int nRows) {
  __shared__ float sW[64][65];
  __shared__ float sRow[4][64];
  const int tid = threadIdx.x;
  for (int i = tid; i < 64 * 64; i += 256) sW[i >> 6][i & 63] = W[i];
  __syncthreads();
  const int wid = tid >> 6, j = tid & 63;
  const int row = blockIdx.x * 4 + wid;
  if (row < nRows) {
    const size_t base = (size_t)row * DIM;
    sRow[wid][j] = io[base + j];
    float acc = b[j];
#pragma unroll
    for (int k = 0; k < 64; ++k) acc = fmaf(sRow[wid][k], sW[j][k], acc);
    io[base + j] = fmaxf(acc, 0.0f);
  }
}

extern "C" void kernel_launch(void* const* d_in, const int* in_sizes, int n_in,
                              void* d_out, int out_size, void* d_ws, size_t ws_size,
                              hipStream_t stream) {
  const float* x = (const float*)d_in[0];
  const int* ei  = (const int*)d_in[1];
  const float* W = (const float*)d_in[2];
  const float* b = (const float*)d_in[3];
  float* out     = (float*)d_out;

  const int nNodes = in_sizes[0] / DIM;  // 100000
  const int nEdges = in_sizes[1] / 2;    // 1600000
  const int nB = (nNodes + BROWS - 1) / BROWS;  // 391

  // ws layout (256B-aligned slabs)
  size_t off = 0;
  auto take = [&](size_t bytes) {
    size_t r = off;
    off += (bytes + 255) & ~(size_t)255;
    return r;
  };
  char* ws = (char*)d_ws;
  int* bhist = (int*)(ws + take(MAXB * 4));
  int* boff  = (int*)(ws + take((MAXB + 1) * 4));
  int* bcur  = (int*)(ws + take(MAXB * 4));
  __hip_bfloat16* Wbf = (__hip_bfloat16*)(ws + take(DIM * DIM * 2));
  int* packed = (int*)(ws + take((size_t)nEdges * 4));

  const bool fastPath =
      (nNodes <= (COLMASK + 1)) && (nB <= MAXB) && (ws_size >= off);

  if (fastPath) {
    const int nChunks = (nEdges + 4095) / 4096;  // 391
    hipMemsetAsync(bhist, 0, (size_t)nB * sizeof(int), stream);
    bucket_hist_kernel<<<nChunks, 256, 0, stream>>>(ei, bhist, nEdges, nB);
    bucket_scan_kernel<<<1, MAXB, 0, stream>>>(bhist, boff, bcur, nB, nEdges);
    partition_kernel<<<nChunks, 1024, 0, stream>>>(ei, bcur, packed, nEdges, nB);
    wprep_kernel<<<(DIM * DIM + 255) / 256, 256, 0, stream>>>(W, Wbf);
    aggregate_gemm_kernel<<<nB, 1024, 0, stream>>>(x, packed, boff, Wbf, b, out, nNodes);
  } else {
    hipMemsetAsync(d_out, 0, (size_t)out_size * sizeof(float), stream);
    scatter_add_kernel<<<(nEdges + 3) / 4, 256, 0, stream>>>(x, ei, out, nEdges);
    linear_relu_inplace_kernel<<<(nNodes + 3) / 4, 256, 0, stream>>>(out, W, b, nNodes);
  }
}

// Round 5
// 136.656 us; speedup vs baseline: 5.3322x; 5.3322x over previous
//
#include <hip/hip_runtime.h>
#include <hip/hip_bf16.h>

#define DIM 64
#define BROWS 128                 // destination rows per bucket
#define BSHIFT 7                  // log2(BROWS)
#define COLBITS 17                // col bits in packed edge (nNodes <= 131072)
#define COLMASK ((1 << COLBITS) - 1)
#define MAXB 1024                 // max buckets supported
#define MAX_EPB 3072              // max edges per bucket (mean 2046, +22 sigma)

typedef __attribute__((ext_vector_type(8))) short bf16x8;  // 8 bf16 = 4 VGPRs
typedef __attribute__((ext_vector_type(4))) float f32x4;

static __device__ __forceinline__ ushort f2bu(float f) {
  __hip_bfloat16 h = __float2bfloat16(f);
  return *reinterpret_cast<const ushort*>(&h);
}

// ---------------------------------------------------------------------------
// A) Bucket histogram: bucket = row >> BSHIFT. Per-WG LDS hist (int atomics),
//    one global atomic per (WG,bucket). 4096 edges per 256-thread WG.
// ---------------------------------------------------------------------------
__global__ __launch_bounds__(256) void bucket_hist_kernel(
    const int* __restrict__ ei, int* __restrict__ bhist, int nEdges, int nB) {
  __shared__ int h[MAXB];
  for (int i = threadIdx.x; i < nB; i += 256) h[i] = 0;
  __syncthreads();
  const int blkBase = blockIdx.x * 4096;
#pragma unroll
  for (int j = 0; j < 4; ++j) {
    int i = blkBase + j * 1024 + threadIdx.x * 4;
    if (i + 4 <= nEdges) {
      int4 r = *(const int4*)(ei + i);
      atomicAdd(&h[r.x >> BSHIFT], 1);
      atomicAdd(&h[r.y >> BSHIFT], 1);
      atomicAdd(&h[r.z >> BSHIFT], 1);
      atomicAdd(&h[r.w >> BSHIFT], 1);
    } else {
      int lim = (nEdges < i + 4) ? nEdges : i + 4;
      for (int k = i; k < lim; ++k) atomicAdd(&h[ei[k] >> BSHIFT], 1);
    }
  }
  __syncthreads();
  for (int i = threadIdx.x; i < nB; i += 256) {
    int c = h[i];
    if (c) atomicAdd(&bhist[i], c);
  }
}

// ---------------------------------------------------------------------------
// B) Exclusive scan of bucket counts (single 1024-thread WG, nB <= 1024).
// ---------------------------------------------------------------------------
__global__ __launch_bounds__(MAXB) void bucket_scan_kernel(
    const int* __restrict__ bhist, int* __restrict__ boff,
    int* __restrict__ bcur, int nB, int nEdges) {
  __shared__ int s[MAXB];
  int t = threadIdx.x;
  int v = (t < nB) ? bhist[t] : 0;
  s[t] = v;
  __syncthreads();
  for (int off = 1; off < MAXB; off <<= 1) {
    int a = (t >= off) ? s[t - off] : 0;
    __syncthreads();
    s[t] += a;
    __syncthreads();
  }
  if (t < nB) {
    int ex = s[t] - v;
    boff[t] = ex;
    bcur[t] = ex;
  }
  if (t == 0) boff[nB] = nEdges;
}

// ---------------------------------------------------------------------------
// C) Partition edges into bucket-contiguous packed ints:
//    packed = (localRow << COLBITS) | col. Per-WG LDS counting + one global
//    reservation per (WG,bucket) -> per-bucket runs -> line-level write
//    locality (no 16x write amplification).
// ---------------------------------------------------------------------------
__global__ __launch_bounds__(1024) void partition_kernel(
    const int* __restrict__ ei, int* __restrict__ bcur,
    int* __restrict__ packed, int nEdges, int nB) {
  __shared__ int h[MAXB];
  __shared__ int base[MAXB];
  const int t = threadIdx.x;
  for (int i = t; i < nB; i += 1024) h[i] = 0;
  __syncthreads();
  const int i0 = blockIdx.x * 4096 + t * 4;
  int4 r;
  const bool full = (i0 + 4 <= nEdges);
  if (full) {
    r = *(const int4*)(ei + i0);
    atomicAdd(&h[r.x >> BSHIFT], 1);
    atomicAdd(&h[r.y >> BSHIFT], 1);
    atomicAdd(&h[r.z >> BSHIFT], 1);
    atomicAdd(&h[r.w >> BSHIFT], 1);
  } else if (i0 < nEdges) {
    for (int k = i0; k < nEdges; ++k) atomicAdd(&h[ei[k] >> BSHIFT], 1);
  }
  __syncthreads();
  for (int i = t; i < nB; i += 1024) {
    int c = h[i];
    base[i] = c ? atomicAdd(&bcur[i], c) : 0;
  }
  __syncthreads();
  for (int i = t; i < nB; i += 1024) h[i] = 0;
  __syncthreads();
  if (full) {
    int4 c4 = *(const int4*)(ei + nEdges + i0);
    int b0 = r.x >> BSHIFT, b1 = r.y >> BSHIFT, b2 = r.z >> BSHIFT, b3 = r.w >> BSHIFT;
    int p0 = base[b0] + atomicAdd(&h[b0], 1);
    int p1 = base[b1] + atomicAdd(&h[b1], 1);
    int p2 = base[b2] + atomicAdd(&h[b2], 1);
    int p3 = base[b3] + atomicAdd(&h[b3], 1);
    packed[p0] = ((r.x & (BROWS - 1)) << COLBITS) | c4.x;
    packed[p1] = ((r.y & (BROWS - 1)) << COLBITS) | c4.y;
    packed[p2] = ((r.z & (BROWS - 1)) << COLBITS) | c4.z;
    packed[p3] = ((r.w & (BROWS - 1)) << COLBITS) | c4.w;
  } else if (i0 < nEdges) {
    for (int k = i0; k < nEdges; ++k) {
      int row = ei[k], col = ei[nEdges + k];
      int b = row >> BSHIFT;
      int p = base[b] + atomicAdd(&h[b], 1);
      packed[p] = ((row & (BROWS - 1)) << COLBITS) | col;
    }
  }
}

// ---------------------------------------------------------------------------
// D) W (f32 row-major [64][64]) -> bf16, same layout.
// ---------------------------------------------------------------------------
__global__ __launch_bounds__(256) void wprep_kernel(
    const float* __restrict__ W, __hip_bfloat16* __restrict__ Wbf) {
  int i = blockIdx.x * 256 + threadIdx.x;
  if (i < DIM * DIM) Wbf[i] = __float2bfloat16(W[i]);
}

// ---------------------------------------------------------------------------
// E) Per-bucket: local CSR in LDS (int cursor atomics only) -> register
//    gather (lane = dim, 8 loads in flight, NO atomics) -> bf16 staging in
//    chunk-XOR-swizzled LDS -> MFMA 16x16x32 + bias + relu -> out.
//    WG = 512 threads = 8 waves; wave w owns rows [w*16, w*16+16).
//
//    Staging swizzle: row r, 16B-chunk c (8 chunks/row) stored at chunk
//    c ^ (r&7). A-frag ds_read_b128 then hits every bank exactly 8 dwords
//    (minimal) instead of 16-way conflicts.
// ---------------------------------------------------------------------------
__global__ __launch_bounds__(512) void bucket_gather_gemm_kernel(
    const float* __restrict__ x, const int* __restrict__ packed,
    const int* __restrict__ boff, const __hip_bfloat16* __restrict__ Wbf,
    const float* __restrict__ bias, float* __restrict__ out, int nNodes) {
  __shared__ int lcsr[MAX_EPB];       // 12 KiB: col indices grouped by row
  __shared__ int lhist[BROWS];        // per-row degree
  __shared__ int loff[BROWS];         // per-row exclusive offset
  __shared__ int lcur[BROWS];         // scatter cursors
  __shared__ int lscan[BROWS];
  __shared__ ushort sA[BROWS * DIM];  // 16 KiB: bf16 aggr, chunk-swizzled

  const int t = threadIdx.x;
  const int bkt = blockIdx.x;
  const int es = boff[bkt], ee = boff[bkt + 1];
  const int cnt = ee - es;
  const int w = t >> 6, lane = t & 63;

  if (t < BROWS) lhist[t] = 0;
  __syncthreads();

  const bool fast = (cnt <= MAX_EPB);  // WG-uniform
  if (fast) {
    // local histogram of rows
    for (int i = es + t; i < ee; i += 512)
      atomicAdd(&lhist[packed[i] >> COLBITS], 1);
    __syncthreads();
    // exclusive scan (Hillis-Steele over 128)
    if (t < BROWS) lscan[t] = lhist[t];
    __syncthreads();
    for (int o = 1; o < BROWS; o <<= 1) {
      int a = (t < BROWS && t >= o) ? lscan[t - o] : 0;
      __syncthreads();
      if (t < BROWS) lscan[t] += a;
      __syncthreads();
    }
    if (t < BROWS) {
      int ex = lscan[t] - lhist[t];
      loff[t] = ex;
      lcur[t] = ex;
    }
    __syncthreads();
    // scatter cols into local CSR
    for (int i = es + t; i < ee; i += 512) {
      int p = packed[i];
      int lr = p >> COLBITS;
      int pos = atomicAdd(&lcur[lr], 1);
      lcsr[pos] = p & COLMASK;
    }
    __syncthreads();
  }

  const float* xl = x + lane;
  const int rbase = w * 16;

  for (int rr = 0; rr < 16; ++rr) {
    const int r = rbase + rr;
    float acc;
    if (fast) {
      const int s0 = loff[r];
      const int deg = lhist[r];
      float a0 = 0.f, a1 = 0.f, a2 = 0.f, a3 = 0.f;
      float a4 = 0.f, a5 = 0.f, a6 = 0.f, a7 = 0.f;
      int e = 0;
      for (; e + 8 <= deg; e += 8) {
        int c0 = lcsr[s0 + e + 0], c1 = lcsr[s0 + e + 1];
        int c2 = lcsr[s0 + e + 2], c3 = lcsr[s0 + e + 3];
        int c4 = lcsr[s0 + e + 4], c5 = lcsr[s0 + e + 5];
        int c6 = lcsr[s0 + e + 6], c7 = lcsr[s0 + e + 7];
        a0 += xl[c0 << 6]; a1 += xl[c1 << 6]; a2 += xl[c2 << 6]; a3 += xl[c3 << 6];
        a4 += xl[c4 << 6]; a5 += xl[c5 << 6]; a6 += xl[c6 << 6]; a7 += xl[c7 << 6];
      }
      acc = ((a0 + a1) + (a2 + a3)) + ((a4 + a5) + (a6 + a7));
      for (; e < deg; ++e) acc += xl[lcsr[s0 + e] << 6];
    } else {
      // overflow bucket (never expected): direct scan of packed range
      acc = 0.f;
      for (int i = es; i < ee; ++i) {
        int p = packed[i];
        if ((p >> COLBITS) == r) acc += xl[(p & COLMASK) << 6];
      }
    }
    // stage bf16 with chunk swizzle: chunk c = lane>>3 -> c ^ (r&7)
    const int cs = (lane >> 3) ^ (r & 7);
    sA[r * DIM + cs * 8 + (lane & 7)] = f2bu(acc);
  }

  // --- MFMA phase (intra-wave only: reads own rows; lgkmcnt auto) ---
  const int rq = lane & 15, kg = lane >> 4;
  const int row = rbase + rq;
  const ushort* pr = &sA[row * DIM];
  bf16x8 A0 = *(const bf16x8*)(pr + (((kg)     ^ (row & 7)) << 3));  // k 0..31 slice
  bf16x8 A1 = *(const bf16x8*)(pr + (((4 + kg) ^ (row & 7)) << 3));  // k 32..63 slice

  f32x4 acc4[4] = {f32x4{0, 0, 0, 0}, f32x4{0, 0, 0, 0},
                   f32x4{0, 0, 0, 0}, f32x4{0, 0, 0, 0}};
#pragma unroll
  for (int jt = 0; jt < 4; ++jt) {
    const ushort* bRow = (const ushort*)Wbf + (jt * 16 + rq) * DIM + kg * 8;
    bf16x8 B0 = *(const bf16x8*)(bRow);
    bf16x8 B1 = *(const bf16x8*)(bRow + 32);
    acc4[jt] = __builtin_amdgcn_mfma_f32_16x16x32_bf16(A0, B0, acc4[jt], 0, 0, 0);
    acc4[jt] = __builtin_amdgcn_mfma_f32_16x16x32_bf16(A1, B1, acc4[jt], 0, 0, 0);
  }

  const int nodeBase = bkt * BROWS + rbase;
#pragma unroll
  for (int jt = 0; jt < 4; ++jt) {
    int j = jt * 16 + rq;
    float bj = bias[j];
#pragma unroll
    for (int q = 0; q < 4; ++q) {
      int node = nodeBase + kg * 4 + q;
      if (node < nNodes) out[(size_t)node * DIM + j] = fmaxf(acc4[jt][q] + bj, 0.f);
    }
  }
}

// ---------------------------------------------------------------------------
// Fallback (nNodes > 131072 or tiny ws): direct atomic scatter + in-place
// linear (round-1 path).
// ---------------------------------------------------------------------------
__global__ __launch_bounds__(256) void scatter_add_kernel(
    const float* __restrict__ x, const int* __restrict__ ei,
    float* __restrict__ aggr, int nEdges) {
  const int lane = threadIdx.x & 63;
  const int e = blockIdx.x * 4 + (threadIdx.x >> 6);
  if (e >= nEdges) return;
  const int row = ei[e];
  const int col = ei[nEdges + e];
  atomicAdd(&aggr[(size_t)row * DIM + lane], x[(size_t)col * DIM + lane]);
}

__global__ __launch_bounds__(256) void linear_relu_inplace_kernel(
    float* __restrict__ io, const float* __restrict__ W,
    const float* __restrict__ b, int nRows) {
  __shared__ float sW[64][65];
  __shared__ float sRow[4][64];
  const int tid = threadIdx.x;
  for (int i = tid; i < 64 * 64; i += 256) sW[i >> 6][i & 63] = W[i];
  __syncthreads();
  const int wid = tid >> 6, j = tid & 63;
  const int row = blockIdx.x * 4 + wid;
  if (row < nRows) {
    const size_t base = (size_t)row * DIM;
    sRow[wid][j] = io[base + j];
    float acc = b[j];
#pragma unroll
    for (int k = 0; k < 64; ++k) acc = fmaf(sRow[wid][k], sW[j][k], acc);
    io[base + j] = fmaxf(acc, 0.0f);
  }
}

extern "C" void kernel_launch(void* const* d_in, const int* in_sizes, int n_in,
                              void* d_out, int out_size, void* d_ws, size_t ws_size,
                              hipStream_t stream) {
  const float* x = (const float*)d_in[0];
  const int* ei  = (const int*)d_in[1];
  const float* W = (const float*)d_in[2];
  const float* b = (const float*)d_in[3];
  float* out     = (float*)d_out;

  const int nNodes = in_sizes[0] / DIM;         // 100000
  const int nEdges = in_sizes[1] / 2;           // 1600000
  const int nB = (nNodes + BROWS - 1) >> BSHIFT;  // 782

  // ws layout (256B-aligned slabs)
  size_t off = 0;
  auto take = [&](size_t bytes) {
    size_t r = off;
    off += (bytes + 255) & ~(size_t)255;
    return r;
  };
  char* ws = (char*)d_ws;
  int* bhist = (int*)(ws + take(MAXB * 4));
  int* boff  = (int*)(ws + take((MAXB + 1) * 4));
  int* bcur  = (int*)(ws + take(MAXB * 4));
  __hip_bfloat16* Wbf = (__hip_bfloat16*)(ws + take(DIM * DIM * 2));
  int* packed = (int*)(ws + take((size_t)nEdges * 4));

  const bool fastPath =
      (nNodes <= (COLMASK + 1)) && (nB <= MAXB) && (ws_size >= off);

  if (fastPath) {
    const int nChunks = (nEdges + 4095) / 4096;  // 391
    hipMemsetAsync(bhist, 0, (size_t)nB * sizeof(int), stream);
    bucket_hist_kernel<<<nChunks, 256, 0, stream>>>(ei, bhist, nEdges, nB);
    bucket_scan_kernel<<<1, MAXB, 0, stream>>>(bhist, boff, bcur, nB, nEdges);
    partition_kernel<<<nChunks, 1024, 0, stream>>>(ei, bcur, packed, nEdges, nB);
    wprep_kernel<<<(DIM * DIM + 255) / 256, 256, 0, stream>>>(W, Wbf);
    bucket_gather_gemm_kernel<<<nB, 512, 0, stream>>>(x, packed, boff, Wbf, b, out, nNodes);
  } else {
    hipMemsetAsync(d_out, 0, (size_t)out_size * sizeof(float), stream);
    scatter_add_kernel<<<(nEdges + 3) / 4, 256, 0, stream>>>(x, ei, out, nEdges);
    linear_relu_inplace_kernel<<<(nNodes + 3) / 4, 256, 0, stream>>>(out, W, b, nNodes);
  }
}

// Round 7
// 108.043 us; speedup vs baseline: 6.7444x; 1.2648x over previous
//
#include <hip/hip_runtime.h>
#include <hip/hip_bf16.h>

#define DIM 64
#define BROWS 64                  // destination rows per bucket
#define BSHIFT 6                  // log2(BROWS)
#define COLBITS 17                // col bits in packed edge (nNodes < 131072)
#define COLMASK ((1 << COLBITS) - 1)
#define MAXB 2048                 // max buckets (nNodes/64)
#define LCSR_CAP 2048             // LDS CSR capacity incl. pad (mean 1024+448)

typedef __attribute__((ext_vector_type(8))) short bf16x8;   // MFMA A/B frag
typedef __attribute__((ext_vector_type(4))) float f32x4;
typedef __attribute__((ext_vector_type(8))) ushort u16x8;   // 16B bf16 store

static __device__ __forceinline__ ushort f2bu(float f) {
  __hip_bfloat16 h = __float2bfloat16(f);
  return *reinterpret_cast<const ushort*>(&h);
}
static __device__ __forceinline__ float bu2f(ushort u) {
  return __uint_as_float(((unsigned)u) << 16);
}

// ---------------------------------------------------------------------------
// P) Prep: x (f32) -> xb (bf16, +1 zero row at index nNodes), W -> Wbf.
//    8 elems/thread, 16B stores. BUGFIX r6: W loop now strided over 256
//    threads (was `tid < 512` in a 256-thread block -> half of W garbage).
// ---------------------------------------------------------------------------
__global__ __launch_bounds__(256) void prep_kernel(
    const float* __restrict__ x, const float* __restrict__ W,
    ushort* __restrict__ xb, ushort* __restrict__ Wbf, int nNodes) {
  const int idx = blockIdx.x * 256 + threadIdx.x;
  const int nx8 = nNodes * DIM / 8;
  if (idx < nx8) {
    const f32x4* p = (const f32x4*)(x + (size_t)idx * 8);
    f32x4 v0 = p[0], v1 = p[1];
    u16x8 o;
    o[0] = f2bu(v0[0]); o[1] = f2bu(v0[1]); o[2] = f2bu(v0[2]); o[3] = f2bu(v0[3]);
    o[4] = f2bu(v1[0]); o[5] = f2bu(v1[1]); o[6] = f2bu(v1[2]); o[7] = f2bu(v1[3]);
    *(u16x8*)(xb + (size_t)idx * 8) = o;
  }
  if (blockIdx.x == 0) {
    // W: 4096 elems, 8 per thread per iter, 2 iters over 256 threads.
    for (int wb = threadIdx.x * 8; wb < DIM * DIM; wb += 256 * 8) {
      u16x8 o;
#pragma unroll
      for (int k = 0; k < 8; ++k) o[k] = f2bu(W[wb + k]);
      *(u16x8*)(Wbf + wb) = o;
    }
    if (threadIdx.x < 8) {    // zero row for pad-gathers
      u16x8 z = {0, 0, 0, 0, 0, 0, 0, 0};
      *(u16x8*)(xb + (size_t)nNodes * DIM + threadIdx.x * 8) = z;
    }
  }
}

// ---------------------------------------------------------------------------
// A) Bucket histogram: bucket = row >> 6. Per-WG LDS hist (int atomics),
//    one global atomic per (WG,bucket). 4096 edges per 256-thread WG.
// ---------------------------------------------------------------------------
__global__ __launch_bounds__(256) void bucket_hist_kernel(
    const int* __restrict__ ei, int* __restrict__ bhist, int nEdges, int nB) {
  __shared__ int h[MAXB];
  for (int i = threadIdx.x; i < nB; i += 256) h[i] = 0;
  __syncthreads();
  const int blkBase = blockIdx.x * 4096;
#pragma unroll
  for (int j = 0; j < 4; ++j) {
    int i = blkBase + j * 1024 + threadIdx.x * 4;
    if (i + 4 <= nEdges) {
      int4 r = *(const int4*)(ei + i);
      atomicAdd(&h[r.x >> BSHIFT], 1);
      atomicAdd(&h[r.y >> BSHIFT], 1);
      atomicAdd(&h[r.z >> BSHIFT], 1);
      atomicAdd(&h[r.w >> BSHIFT], 1);
    } else {
      int lim = (nEdges < i + 4) ? nEdges : i + 4;
      for (int k = i; k < lim; ++k) atomicAdd(&h[ei[k] >> BSHIFT], 1);
    }
  }
  __syncthreads();
  for (int i = threadIdx.x; i < nB; i += 256) {
    int c = h[i];
    if (c) atomicAdd(&bhist[i], c);
  }
}

// ---------------------------------------------------------------------------
// B) Exclusive scan of bucket counts (1024 threads, 2 elems each, nB<=2048).
// ---------------------------------------------------------------------------
__global__ __launch_bounds__(1024) void bucket_scan_kernel(
    const int* __restrict__ bhist, int* __restrict__ boff,
    int* __restrict__ bcur, int nB, int nEdges) {
  __shared__ int s[1024];
  const int t = threadIdx.x;
  int a = (2 * t < nB) ? bhist[2 * t] : 0;
  int b = (2 * t + 1 < nB) ? bhist[2 * t + 1] : 0;
  int p = a + b;
  s[t] = p;
  __syncthreads();
  for (int o = 1; o < 1024; o <<= 1) {
    int v = (t >= o) ? s[t - o] : 0;
    __syncthreads();
    s[t] += v;
    __syncthreads();
  }
  int excl = s[t] - p;
  if (2 * t < nB)     { boff[2 * t] = excl;         bcur[2 * t] = excl; }
  if (2 * t + 1 < nB) { boff[2 * t + 1] = excl + a; bcur[2 * t + 1] = excl + a; }
  if (t == 0) boff[nB] = nEdges;
}

// ---------------------------------------------------------------------------
// C) Partition edges into bucket-contiguous packed ints:
//    packed = (localRow << COLBITS) | col. Per-WG LDS counting + one global
//    reservation per (WG,bucket) -> line-level write locality.
// ---------------------------------------------------------------------------
__global__ __launch_bounds__(1024) void partition_kernel(
    const int* __restrict__ ei, int* __restrict__ bcur,
    int* __restrict__ packed, int nEdges, int nB) {
  __shared__ int h[MAXB];
  __shared__ int base[MAXB];
  const int t = threadIdx.x;
  for (int i = t; i < nB; i += 1024) h[i] = 0;
  __syncthreads();
  const int i0 = blockIdx.x * 4096 + t * 4;
  int4 r;
  const bool full = (i0 + 4 <= nEdges);
  if (full) {
    r = *(const int4*)(ei + i0);
    atomicAdd(&h[r.x >> BSHIFT], 1);
    atomicAdd(&h[r.y >> BSHIFT], 1);
    atomicAdd(&h[r.z >> BSHIFT], 1);
    atomicAdd(&h[r.w >> BSHIFT], 1);
  } else if (i0 < nEdges) {
    for (int k = i0; k < nEdges; ++k) atomicAdd(&h[ei[k] >> BSHIFT], 1);
  }
  __syncthreads();
  for (int i = t; i < nB; i += 1024) {
    int c = h[i];
    base[i] = c ? atomicAdd(&bcur[i], c) : 0;
  }
  __syncthreads();
  for (int i = t; i < nB; i += 1024) h[i] = 0;
  __syncthreads();
  if (full) {
    int4 c4 = *(const int4*)(ei + nEdges + i0);
    int b0 = r.x >> BSHIFT, b1 = r.y >> BSHIFT, b2 = r.z >> BSHIFT, b3 = r.w >> BSHIFT;
    int p0 = base[b0] + atomicAdd(&h[b0], 1);
    int p1 = base[b1] + atomicAdd(&h[b1], 1);
    int p2 = base[b2] + atomicAdd(&h[b2], 1);
    int p3 = base[b3] + atomicAdd(&h[b3], 1);
    packed[p0] = ((r.x & (BROWS - 1)) << COLBITS) | c4.x;
    packed[p1] = ((r.y & (BROWS - 1)) << COLBITS) | c4.y;
    packed[p2] = ((r.z & (BROWS - 1)) << COLBITS) | c4.z;
    packed[p3] = ((r.w & (BROWS - 1)) << COLBITS) | c4.w;
  } else if (i0 < nEdges) {
    for (int k = i0; k < nEdges; ++k) {
      int row = ei[k], col = ei[nEdges + k];
      int b = row >> BSHIFT;
      int p = base[b] + atomicAdd(&h[b], 1);
      packed[p] = ((row & (BROWS - 1)) << COLBITS) | col;
    }
  }
}

// ---------------------------------------------------------------------------
// E) Per-bucket (64 rows, 256 threads = 4 waves):
//    1. local CSR in LDS, per-row slots padded to multiple of 8 with a
//       dummy col = nNodes (zero row in xb) -> tail-free gather.
//    2. register gather, lane = dim, 16 bf16 loads in flight per row.
//    3. bf16 staging in chunk-XOR-swizzled LDS -> MFMA 16x16x32 + bias +
//       relu -> out (layout verified rounds 3-5).
// ---------------------------------------------------------------------------
__global__ __launch_bounds__(256) void bucket_gather_gemm_kernel(
    const ushort* __restrict__ xb, const int* __restrict__ packed,
    const int* __restrict__ boff, const ushort* __restrict__ Wbf,
    const float* __restrict__ bias, float* __restrict__ out, int nNodes) {
  __shared__ int lcsr[LCSR_CAP];      // 8 KiB
  __shared__ int lhist[BROWS];
  __shared__ int loff[BROWS];
  __shared__ int lcur[BROWS];
  __shared__ ushort sA[BROWS * DIM];  // 8 KiB

  const int t = threadIdx.x;
  const int bkt = blockIdx.x;
  const int es = boff[bkt], ee = boff[bkt + 1];
  const int cnt = ee - es;
  const int w = t >> 6, lane = t & 63;

  if (t < BROWS) lhist[t] = 0;
  __syncthreads();

  const bool fast = (cnt + BROWS * 7 <= LCSR_CAP);  // WG-uniform
  if (fast) {
    for (int i = es + t; i < ee; i += 256)
      atomicAdd(&lhist[packed[i] >> COLBITS], 1);
    __syncthreads();
    // exclusive scan of PADDED degrees (round up to multiple of 8)
    int rd = (t < BROWS) ? ((lhist[t] + 7) & ~7) : 0;
    if (t < BROWS) lcur[t] = rd;
    __syncthreads();
    for (int o = 1; o < BROWS; o <<= 1) {
      int v = (t < BROWS && t >= o) ? lcur[t - o] : 0;
      __syncthreads();
      if (t < BROWS) lcur[t] += v;
      __syncthreads();
    }
    if (t < BROWS) loff[t] = lcur[t] - rd;
    __syncthreads();
    if (t < BROWS) lcur[t] = loff[t];
    __syncthreads();
    // scatter real cols
    for (int i = es + t; i < ee; i += 256) {
      int p = packed[i];
      int lr = p >> COLBITS;
      int pos = atomicAdd(&lcur[lr], 1);
      lcsr[pos] = p & COLMASK;
    }
    __syncthreads();
    // fill pads with dummy col (zero row)
    if (t < BROWS) {
      int d = lhist[t], rdg = (d + 7) & ~7, o0 = loff[t];
      for (int k = d; k < rdg; ++k) lcsr[o0 + k] = nNodes;
    }
    __syncthreads();
  }

  const ushort* xl = xb + lane;
  const int rbase = w << 4;

  for (int rr = 0; rr < 16; ++rr) {
    const int r = rbase + rr;
    float acc = 0.f;
    if (fast) {
      const int s0 = loff[r];
      const int rdg = (lhist[r] + 7) & ~7;  // padded degree, multiple of 8
      const int* lp = lcsr + s0;
      int e = 0;
      for (; e + 16 <= rdg; e += 16) {
        int c[16];
#pragma unroll
        for (int j = 0; j < 16; ++j) c[j] = lp[e + j];
        float v[16];
#pragma unroll
        for (int j = 0; j < 16; ++j) v[j] = bu2f(xl[c[j] << 6]);
        acc += (((v[0] + v[1]) + (v[2] + v[3])) + ((v[4] + v[5]) + (v[6] + v[7]))) +
               (((v[8] + v[9]) + (v[10] + v[11])) + ((v[12] + v[13]) + (v[14] + v[15])));
      }
      if (e < rdg) {  // exactly one 8-batch remains (rdg % 16 == 8)
        int c[8];
#pragma unroll
        for (int j = 0; j < 8; ++j) c[j] = lp[e + j];
        float v[8];
#pragma unroll
        for (int j = 0; j < 8; ++j) v[j] = bu2f(xl[c[j] << 6]);
        acc += ((v[0] + v[1]) + (v[2] + v[3])) + ((v[4] + v[5]) + (v[6] + v[7]));
      }
    } else {
      // overflow backstop (statistically never): scan the packed range
      for (int i = es; i < ee; ++i) {
        int p = packed[i];
        if ((p >> COLBITS) == r) acc += bu2f(xl[(p & COLMASK) << 6]);
      }
    }
    // stage bf16, chunk c = lane>>3 swizzled to c ^ (r&7)
    const int cs = (lane >> 3) ^ (r & 7);
    sA[r * DIM + cs * 8 + (lane & 7)] = f2bu(acc);
  }

  // --- MFMA phase (intra-wave LDS only; no barrier needed) ---
  const int rq = lane & 15, kg = lane >> 4;
  const int row = rbase + rq;
  const ushort* pr = &sA[row * DIM];
  bf16x8 A0 = *(const bf16x8*)(pr + (((kg) ^ (row & 7)) << 3));      // k 0..31
  bf16x8 A1 = *(const bf16x8*)(pr + (((4 + kg) ^ (row & 7)) << 3));  // k 32..63

  f32x4 acc4[4] = {f32x4{0, 0, 0, 0}, f32x4{0, 0, 0, 0},
                   f32x4{0, 0, 0, 0}, f32x4{0, 0, 0, 0}};
#pragma unroll
  for (int jt = 0; jt < 4; ++jt) {
    const ushort* bRow = Wbf + (jt * 16 + rq) * DIM + kg * 8;
    bf16x8 B0 = *(const bf16x8*)(bRow);
    bf16x8 B1 = *(const bf16x8*)(bRow + 32);
    acc4[jt] = __builtin_amdgcn_mfma_f32_16x16x32_bf16(A0, B0, acc4[jt], 0, 0, 0);
    acc4[jt] = __builtin_amdgcn_mfma_f32_16x16x32_bf16(A1, B1, acc4[jt], 0, 0, 0);
  }

  const int nodeBase = bkt * BROWS + rbase;
#pragma unroll
  for (int jt = 0; jt < 4; ++jt) {
    int j = jt * 16 + rq;
    float bj = bias[j];
#pragma unroll
    for (int q = 0; q < 4; ++q) {
      int node = nodeBase + kg * 4 + q;
      if (node < nNodes) out[(size_t)node * DIM + j] = fmaxf(acc4[jt][q] + bj, 0.f);
    }
  }
}

// ---------------------------------------------------------------------------
// Fallback (huge nNodes or tiny ws): direct atomic scatter + in-place linear.
// ---------------------------------------------------------------------------
__global__ __launch_bounds__(256) void scatter_add_kernel(
    const float* __restrict__ x, const int* __restrict__ ei,
    float* __restrict__ aggr, int nEdges) {
  const int lane = threadIdx.x & 63;
  const int e = blockIdx.x * 4 + (threadIdx.x >> 6);
  if (e >= nEdges) return;
  const int row = ei[e];
  const int col = ei[nEdges + e];
  atomicAdd(&aggr[(size_t)row * DIM + lane], x[(size_t)col * DIM + lane]);
}

__global__ __launch_bounds__(256) void linear_relu_inplace_kernel(
    float* __restrict__ io, const float* __restrict__ W,
    const float* __restrict__ b, int nRows) {
  __shared__ float sW[64][65];
  __shared__ float sRow[4][64];
  const int tid = threadIdx.x;
  for (int i = tid; i < 64 * 64; i += 256) sW[i >> 6][i & 63] = W[i];
  __syncthreads();
  const int wid = tid >> 6, j = tid & 63;
  const int row = blockIdx.x * 4 + wid;
  if (row < nRows) {
    const size_t base = (size_t)row * DIM;
    sRow[wid][j] = io[base + j];
    float acc = b[j];
#pragma unroll
    for (int k = 0; k < 64; ++k) acc = fmaf(sRow[wid][k], sW[j][k], acc);
    io[base + j] = fmaxf(acc, 0.0f);
  }
}

extern "C" void kernel_launch(void* const* d_in, const int* in_sizes, int n_in,
                              void* d_out, int out_size, void* d_ws, size_t ws_size,
                              hipStream_t stream) {
  const float* x = (const float*)d_in[0];
  const int* ei  = (const int*)d_in[1];
  const float* W = (const float*)d_in[2];
  const float* b = (const float*)d_in[3];
  float* out     = (float*)d_out;

  const int nNodes = in_sizes[0] / DIM;           // 100000
  const int nEdges = in_sizes[1] / 2;             // 1600000
  const int nB = (nNodes + BROWS - 1) >> BSHIFT;  // 1563

  // ws layout (256B-aligned slabs) — total ~19.3 MB
  size_t off = 0;
  auto take = [&](size_t bytes) {
    size_t r = off;
    off += (bytes + 255) & ~(size_t)255;
    return r;
  };
  char* ws = (char*)d_ws;
  int* bhist = (int*)(ws + take(MAXB * 4));
  int* boff  = (int*)(ws + take((MAXB + 1) * 4));
  int* bcur  = (int*)(ws + take(MAXB * 4));
  ushort* Wbf = (ushort*)(ws + take(DIM * DIM * 2));
  ushort* xb  = (ushort*)(ws + take((size_t)(nNodes + 1) * DIM * 2));
  int* packed = (int*)(ws + take((size_t)nEdges * 4));

  const bool fastPath =
      (nNodes < (1 << COLBITS)) && (nB <= MAXB) && (ws_size >= off);

  if (fastPath) {
    const int nChunks = (nEdges + 4095) / 4096;  // 391
    hipMemsetAsync(bhist, 0, (size_t)nB * sizeof(int), stream);
    prep_kernel<<<(nNodes * DIM / 8 + 255) / 256, 256, 0, stream>>>(x, W, xb, Wbf, nNodes);
    bucket_hist_kernel<<<nChunks, 256, 0, stream>>>(ei, bhist, nEdges, nB);
    bucket_scan_kernel<<<1, 1024, 0, stream>>>(bhist, boff, bcur, nB, nEdges);
    partition_kernel<<<nChunks, 1024, 0, stream>>>(ei, bcur, packed, nEdges, nB);
    bucket_gather_gemm_kernel<<<nB, 256, 0, stream>>>(xb, packed, boff, Wbf, b, out, nNodes);
  } else {
    hipMemsetAsync(d_out, 0, (size_t)out_size * sizeof(float), stream);
    scatter_add_kernel<<<(nEdges + 3) / 4, 256, 0, stream>>>(x, ei, out, nEdges);
    linear_relu_inplace_kernel<<<(nNodes + 3) / 4, 256, 0, stream>>>(out, W, b, nNodes);
  }
}

// Round 8
// 89.131 us; speedup vs baseline: 8.1754x; 1.2122x over previous
//
#include <hip/hip_runtime.h>
#include <hip/hip_bf16.h>

#define DIM 64
#define BROWS 32                  // destination rows per bucket
#define BSHIFT 5                  // log2(BROWS)
#define COLBITS 17                // col bits in packed edge (nNodes < 131072)
#define COLMASK ((1 << COLBITS) - 1)
#define MAXB 4096                 // max buckets (nNodes/32)
#define LCSR_CAP 1024             // LDS CSR capacity incl. pad (mean 512)
#define HCHUNK 8192               // edges per hist/partition WG

typedef __attribute__((ext_vector_type(8))) short bf16x8;   // MFMA A/B frag
typedef __attribute__((ext_vector_type(4))) float f32x4;
typedef __attribute__((ext_vector_type(8))) ushort u16x8;   // 16B bf16 store

static __device__ __forceinline__ ushort f2bu(float f) {
  __hip_bfloat16 h = __float2bfloat16(f);
  return *reinterpret_cast<const ushort*>(&h);
}
static __device__ __forceinline__ float bu2f(ushort u) {
  return __uint_as_float(((unsigned)u) << 16);
}

// ---------------------------------------------------------------------------
// P) Fused prep + bucket-histogram.
//    All blocks: x (f32) -> xb (bf16, +1 zero row at index nNodes), 8/thread.
//    Block 0: W -> Wbf.  Blocks < nHB: LDS histogram of HCHUNK edges each.
// ---------------------------------------------------------------------------
__global__ __launch_bounds__(256) void prep_hist_kernel(
    const float* __restrict__ x, const float* __restrict__ W,
    const int* __restrict__ ei, ushort* __restrict__ xb,
    ushort* __restrict__ Wbf, int* __restrict__ bhist,
    int nNodes, int nEdges, int nB, int nHB) {
  __shared__ int h[MAXB];  // 16 KiB
  const int t = threadIdx.x;
  const int idx = blockIdx.x * 256 + t;
  const int nx8 = nNodes * DIM / 8;
  if (idx < nx8) {
    const f32x4* p = (const f32x4*)(x + (size_t)idx * 8);
    f32x4 v0 = p[0], v1 = p[1];
    u16x8 o;
    o[0] = f2bu(v0[0]); o[1] = f2bu(v0[1]); o[2] = f2bu(v0[2]); o[3] = f2bu(v0[3]);
    o[4] = f2bu(v1[0]); o[5] = f2bu(v1[1]); o[6] = f2bu(v1[2]); o[7] = f2bu(v1[3]);
    *(u16x8*)(xb + (size_t)idx * 8) = o;
  }
  if (blockIdx.x == 0) {
    for (int wb = t * 8; wb < DIM * DIM; wb += 256 * 8) {
      u16x8 o;
#pragma unroll
      for (int k = 0; k < 8; ++k) o[k] = f2bu(W[wb + k]);
      *(u16x8*)(Wbf + wb) = o;
    }
    if (t < 8) {
      u16x8 z = {0, 0, 0, 0, 0, 0, 0, 0};
      *(u16x8*)(xb + (size_t)nNodes * DIM + t * 8) = z;
    }
  }
  if (blockIdx.x < nHB) {   // block-uniform branch (syncthreads legal inside)
    for (int i = t; i < nB; i += 256) h[i] = 0;
    __syncthreads();
    const int eb = blockIdx.x * HCHUNK + t * 32;
#pragma unroll
    for (int k = 0; k < 8; ++k) {
      int i = eb + k * 4;
      if (i + 4 <= nEdges) {
        int4 r = *(const int4*)(ei + i);
        atomicAdd(&h[r.x >> BSHIFT], 1);
        atomicAdd(&h[r.y >> BSHIFT], 1);
        atomicAdd(&h[r.z >> BSHIFT], 1);
        atomicAdd(&h[r.w >> BSHIFT], 1);
      } else {
        int lim = (nEdges < i + 4) ? nEdges : i + 4;
        for (int q = i; q < lim; ++q) atomicAdd(&h[ei[q] >> BSHIFT], 1);
      }
    }
    __syncthreads();
    for (int i = t; i < nB; i += 256) {
      int c = h[i];
      if (c) atomicAdd(&bhist[i], c);
    }
  }
}

// ---------------------------------------------------------------------------
// B) Exclusive scan of bucket counts (1024 threads, 4 contiguous elems each).
// ---------------------------------------------------------------------------
__global__ __launch_bounds__(1024) void bucket_scan_kernel(
    const int* __restrict__ bhist, int* __restrict__ boff,
    int* __restrict__ bcur, int nB, int nEdges) {
  __shared__ int s[1024];
  const int t = threadIdx.x;
  const int b4 = t * 4;
  int v0 = (b4 + 0 < nB) ? bhist[b4 + 0] : 0;
  int v1 = (b4 + 1 < nB) ? bhist[b4 + 1] : 0;
  int v2 = (b4 + 2 < nB) ? bhist[b4 + 2] : 0;
  int v3 = (b4 + 3 < nB) ? bhist[b4 + 3] : 0;
  int p = v0 + v1 + v2 + v3;
  s[t] = p;
  __syncthreads();
  for (int o = 1; o < 1024; o <<= 1) {
    int a = (t >= o) ? s[t - o] : 0;
    __syncthreads();
    s[t] += a;
    __syncthreads();
  }
  int run = s[t] - p;
  if (b4 + 0 < nB) { boff[b4 + 0] = run; bcur[b4 + 0] = run; run += v0; }
  if (b4 + 1 < nB) { boff[b4 + 1] = run; bcur[b4 + 1] = run; run += v1; }
  if (b4 + 2 < nB) { boff[b4 + 2] = run; bcur[b4 + 2] = run; run += v2; }
  if (b4 + 3 < nB) { boff[b4 + 3] = run; bcur[b4 + 3] = run; run += v3; }
  if (t == 0) boff[nB] = nEdges;
}

// ---------------------------------------------------------------------------
// C) Partition: packed = (localRow << COLBITS) | col, bucket-contiguous.
//    1024 threads x 8 edges = 8192/WG: halves reservation atomics vs r7,
//    keeps per-bucket write-run locality.
// ---------------------------------------------------------------------------
__global__ __launch_bounds__(1024) void partition_kernel(
    const int* __restrict__ ei, int* __restrict__ bcur,
    int* __restrict__ packed, int nEdges, int nB) {
  __shared__ int h[MAXB];     // 16 KiB
  __shared__ int base[MAXB];  // 16 KiB
  const int t = threadIdx.x;
  for (int i = t; i < nB; i += 1024) h[i] = 0;
  __syncthreads();
  const int i0 = blockIdx.x * HCHUNK + t * 8;
  int4 ra, rb;
  const bool full = (i0 + 8 <= nEdges);
  if (full) {
    ra = *(const int4*)(ei + i0);
    rb = *(const int4*)(ei + i0 + 4);
    atomicAdd(&h[ra.x >> BSHIFT], 1); atomicAdd(&h[ra.y >> BSHIFT], 1);
    atomicAdd(&h[ra.z >> BSHIFT], 1); atomicAdd(&h[ra.w >> BSHIFT], 1);
    atomicAdd(&h[rb.x >> BSHIFT], 1); atomicAdd(&h[rb.y >> BSHIFT], 1);
    atomicAdd(&h[rb.z >> BSHIFT], 1); atomicAdd(&h[rb.w >> BSHIFT], 1);
  } else if (i0 < nEdges) {
    for (int k = i0; k < nEdges; ++k) atomicAdd(&h[ei[k] >> BSHIFT], 1);
  }
  __syncthreads();
  for (int i = t; i < nB; i += 1024) {
    int c = h[i];
    base[i] = c ? atomicAdd(&bcur[i], c) : 0;
  }
  __syncthreads();
  for (int i = t; i < nB; i += 1024) h[i] = 0;
  __syncthreads();
  if (full) {
    int4 ca = *(const int4*)(ei + nEdges + i0);
    int4 cb = *(const int4*)(ei + nEdges + i0 + 4);
#define PUT(RR, CC)                                             \
    {                                                           \
      int b_ = (RR) >> BSHIFT;                                  \
      int pos_ = base[b_] + atomicAdd(&h[b_], 1);               \
      packed[pos_] = (((RR) & (BROWS - 1)) << COLBITS) | (CC);  \
    }
    PUT(ra.x, ca.x) PUT(ra.y, ca.y) PUT(ra.z, ca.z) PUT(ra.w, ca.w)
    PUT(rb.x, cb.x) PUT(rb.y, cb.y) PUT(rb.z, cb.z) PUT(rb.w, cb.w)
#undef PUT
  } else if (i0 < nEdges) {
    for (int k = i0; k < nEdges; ++k) {
      int row = ei[k], col = ei[nEdges + k];
      int b = row >> BSHIFT;
      int pos = base[b] + atomicAdd(&h[b], 1);
      packed[pos] = ((row & (BROWS - 1)) << COLBITS) | col;
    }
  }
}

// ---------------------------------------------------------------------------
// E) Per-bucket (32 rows, 128 threads = 2 waves; wave w owns rows w*16..+15):
//    1. LDS CSR: per-row regions padded to multiple of 8 (min 8) with dummy
//       col = nNodes (zero row) -> every wave walks one contiguous batch
//       stream, 16+ batches, no tails.
//    2. PAIR-GATHER: lanes 0-31 = even-slot edge, lanes 32-63 = odd-slot;
//       each lane loads a uint (2 dims) -> 1 vmem instr per 2 edges.
//       Depth-2 software pipeline (vA/vB) keeps 4-8 loads in flight through
//       row boundaries; row finalize = 2x shfl_xor(32) + packed LDS store.
//    3. bf16 staging chunk-XOR-swizzled -> MFMA 16x16x32 + bias + relu.
// ---------------------------------------------------------------------------
__global__ __launch_bounds__(128) void bucket_gather_gemm_kernel(
    const uint* __restrict__ xw, const int* __restrict__ packed,
    const int* __restrict__ boff, const ushort* __restrict__ Wbf,
    const float* __restrict__ bias, float* __restrict__ out, int nNodes) {
  __shared__ int lcsr[LCSR_CAP];       // 4 KiB
  __shared__ int lhist[BROWS];
  __shared__ int loff[BROWS + 1];
  __shared__ int lcur[BROWS];
  __shared__ ushort sA[BROWS * DIM];   // 4 KiB

  const int t = threadIdx.x;
  const int bkt = blockIdx.x;
  const int es = boff[bkt], ee = boff[bkt + 1];
  const int cnt = ee - es;
  const int w = t >> 6, lane = t & 63;

  if (t < BROWS) lhist[t] = 0;
  __syncthreads();

  const bool fast = (cnt + BROWS * 8 <= LCSR_CAP);  // WG-uniform
  if (fast) {
    for (int i = es + t; i < ee; i += 128)
      atomicAdd(&lhist[packed[i] >> COLBITS], 1);
    __syncthreads();
    // scan of padded degrees (multiple of 8, minimum 8)
    int rd = 0;
    if (t < BROWS) {
      rd = (lhist[t] + 7) & ~7;
      if (rd == 0) rd = 8;
      lcur[t] = rd;
    }
    __syncthreads();
    for (int o = 1; o < BROWS; o <<= 1) {
      int v = (t < BROWS && t >= o) ? lcur[t - o] : 0;
      __syncthreads();
      if (t < BROWS) lcur[t] += v;
      __syncthreads();
    }
    if (t < BROWS) loff[t] = lcur[t] - rd;
    if (t == BROWS - 1) loff[BROWS] = lcur[t];
    __syncthreads();
    if (t < BROWS) lcur[t] = loff[t];
    __syncthreads();
    for (int i = es + t; i < ee; i += 128) {
      int p = packed[i];
      int lr = p >> COLBITS;
      int pos = atomicAdd(&lcur[lr], 1);
      lcsr[pos] = p & COLMASK;
    }
    __syncthreads();
    if (t < BROWS) {
      int d = lhist[t];
      int rdg = (d + 7) & ~7;
      if (rdg == 0) rdg = 8;
      int o0 = loff[t];
      for (int k = d; k < rdg; ++k) lcsr[o0 + k] = nNodes;
    }
    __syncthreads();
  }

  const int rbase = w << 4;

  if (fast) {
    const int half = lane >> 5;      // 0: even-slot edge, 1: odd-slot
    const int m = lane & 31;         // dim-pair index: dims 2m, 2m+1

#define ISSUE(v, E)                                  \
    {                                                \
      int c0_ = lcsr[(E) + 0 + half];                \
      int c1_ = lcsr[(E) + 2 + half];                \
      int c2_ = lcsr[(E) + 4 + half];                \
      int c3_ = lcsr[(E) + 6 + half];                \
      v##0 = xw[((size_t)c0_ << 5) + m];             \
      v##1 = xw[((size_t)c1_ << 5) + m];             \
      v##2 = xw[((size_t)c2_ << 5) + m];             \
      v##3 = xw[((size_t)c3_ << 5) + m];             \
    }
#define CONSUME(v)                                                          \
    {                                                                       \
      float l01 = __uint_as_float(v##0 << 16) + __uint_as_float(v##1 << 16);\
      float l23 = __uint_as_float(v##2 << 16) + __uint_as_float(v##3 << 16);\
      aLo += l01 + l23;                                                     \
      float h01 = __uint_as_float(v##0 & 0xffff0000u) +                     \
                  __uint_as_float(v##1 & 0xffff0000u);                      \
      float h23 = __uint_as_float(v##2 & 0xffff0000u) +                     \
                  __uint_as_float(v##3 & 0xffff0000u);                      \
      aHi += h01 + h23;                                                     \
    }

    int r = rbase;
    int rEnd = loff[r + 1];
    const int eBeg = loff[rbase];
    const int eEndW = loff[rbase + 16];
    float aLo = 0.f, aHi = 0.f;
    uint vA0, vA1, vA2, vA3, vB0, vB1, vB2, vB3;

    ISSUE(vA, eBeg)                      // >=16 batches per wave: always valid
    ISSUE(vB, eBeg + 8)
    bool useA = true;
    for (int e = eBeg; e < eEndW; e += 8) {
      if (useA) {
        CONSUME(vA)
        if (e + 16 < eEndW) ISSUE(vA, e + 16)
      } else {
        CONSUME(vB)
        if (e + 16 < eEndW) ISSUE(vB, e + 16)
      }
      useA = !useA;
      if (e + 8 == rEnd) {               // row r complete
        float t0 = aLo + __shfl_xor(aLo, 32);
        float t1 = aHi + __shfl_xor(aHi, 32);
        if (lane < 32) {
          uint pk = (((uint)f2bu(t1)) << 16) | (uint)f2bu(t0);
          int cs = (m >> 2) ^ (r & 7);
          ((uint*)sA)[r * 32 + cs * 4 + (m & 3)] = pk;
        }
        aLo = 0.f; aHi = 0.f;
        ++r;
        rEnd = (r < rbase + 16) ? loff[r + 1] : 0x7fffffff;
      }
    }
#undef ISSUE
#undef CONSUME
  } else {
    // backstop (statistically never): scan packed range per row
    const ushort* xs = (const ushort*)xw;
    for (int rr = 0; rr < 16; ++rr) {
      int r = rbase + rr;
      float acc = 0.f;
      for (int i = es; i < ee; ++i) {
        int p = packed[i];
        if ((p >> COLBITS) == r)
          acc += bu2f(xs[((size_t)(p & COLMASK) << 6) + lane]);
      }
      int cs = (lane >> 3) ^ (r & 7);
      sA[r * DIM + cs * 8 + (lane & 7)] = f2bu(acc);
    }
  }

  // --- MFMA phase (intra-wave LDS only; no barrier needed) ---
  const int rq = lane & 15, kg = lane >> 4;
  const int row = rbase + rq;
  const ushort* pr = &sA[row * DIM];
  bf16x8 A0 = *(const bf16x8*)(pr + (((kg) ^ (row & 7)) << 3));      // k 0..31
  bf16x8 A1 = *(const bf16x8*)(pr + (((4 + kg) ^ (row & 7)) << 3));  // k 32..63

  f32x4 acc4[4] = {f32x4{0, 0, 0, 0}, f32x4{0, 0, 0, 0},
                   f32x4{0, 0, 0, 0}, f32x4{0, 0, 0, 0}};
#pragma unroll
  for (int jt = 0; jt < 4; ++jt) {
    const ushort* bRow = Wbf + (jt * 16 + rq) * DIM + kg * 8;
    bf16x8 B0 = *(const bf16x8*)(bRow);
    bf16x8 B1 = *(const bf16x8*)(bRow + 32);
    acc4[jt] = __builtin_amdgcn_mfma_f32_16x16x32_bf16(A0, B0, acc4[jt], 0, 0, 0);
    acc4[jt] = __builtin_amdgcn_mfma_f32_16x16x32_bf16(A1, B1, acc4[jt], 0, 0, 0);
  }

  const int nodeBase = bkt * BROWS + rbase;
#pragma unroll
  for (int jt = 0; jt < 4; ++jt) {
    int j = jt * 16 + rq;
    float bj = bias[j];
#pragma unroll
    for (int q = 0; q < 4; ++q) {
      int node = nodeBase + kg * 4 + q;
      if (node < nNodes) out[(size_t)node * DIM + j] = fmaxf(acc4[jt][q] + bj, 0.f);
    }
  }
}

// ---------------------------------------------------------------------------
// Fallback (huge nNodes or tiny ws): direct atomic scatter + in-place linear.
// ---------------------------------------------------------------------------
__global__ __launch_bounds__(256) void scatter_add_kernel(
    const float* __restrict__ x, const int* __restrict__ ei,
    float* __restrict__ aggr, int nEdges) {
  const int lane = threadIdx.x & 63;
  const int e = blockIdx.x * 4 + (threadIdx.x >> 6);
  if (e >= nEdges) return;
  const int row = ei[e];
  const int col = ei[nEdges + e];
  atomicAdd(&aggr[(size_t)row * DIM + lane], x[(size_t)col * DIM + lane]);
}

__global__ __launch_bounds__(256) void linear_relu_inplace_kernel(
    float* __restrict__ io, const float* __restrict__ W,
    const float* __restrict__ b, int nRows) {
  __shared__ float sW[64][65];
  __shared__ float sRow[4][64];
  const int tid = threadIdx.x;
  for (int i = tid; i < 64 * 64; i += 256) sW[i >> 6][i & 63] = W[i];
  __syncthreads();
  const int wid = tid >> 6, j = tid & 63;
  const int row = blockIdx.x * 4 + wid;
  if (row < nRows) {
    const size_t base = (size_t)row * DIM;
    sRow[wid][j] = io[base + j];
    float acc = b[j];
#pragma unroll
    for (int k = 0; k < 64; ++k) acc = fmaf(sRow[wid][k], sW[j][k], acc);
    io[base + j] = fmaxf(acc, 0.0f);
  }
}

extern "C" void kernel_launch(void* const* d_in, const int* in_sizes, int n_in,
                              void* d_out, int out_size, void* d_ws, size_t ws_size,
                              hipStream_t stream) {
  const float* x = (const float*)d_in[0];
  const int* ei  = (const int*)d_in[1];
  const float* W = (const float*)d_in[2];
  const float* b = (const float*)d_in[3];
  float* out     = (float*)d_out;

  const int nNodes = in_sizes[0] / DIM;           // 100000
  const int nEdges = in_sizes[1] / 2;             // 1600000
  const int nB = (nNodes + BROWS - 1) >> BSHIFT;  // 3125

  // ws layout (256B-aligned slabs) — total ~19.3 MB
  size_t off = 0;
  auto take = [&](size_t bytes) {
    size_t r = off;
    off += (bytes + 255) & ~(size_t)255;
    return r;
  };
  char* ws = (char*)d_ws;
  int* bhist = (int*)(ws + take(MAXB * 4));
  int* boff  = (int*)(ws + take((MAXB + 1) * 4));
  int* bcur  = (int*)(ws + take(MAXB * 4));
  ushort* Wbf = (ushort*)(ws + take(DIM * DIM * 2));
  ushort* xb  = (ushort*)(ws + take((size_t)(nNodes + 1) * DIM * 2));
  int* packed = (int*)(ws + take((size_t)nEdges * 4));

  const bool fastPath =
      (nNodes < (1 << COLBITS)) && (nB <= MAXB) && (ws_size >= off);

  if (fastPath) {
    const int nHB = (nEdges + HCHUNK - 1) / HCHUNK;         // 196
    const int nPrep = (nNodes * DIM / 8 + 255) / 256;       // 3125
    const int gPrep = (nPrep > nHB) ? nPrep : nHB;
    hipMemsetAsync(bhist, 0, (size_t)nB * sizeof(int), stream);
    prep_hist_kernel<<<gPrep, 256, 0, stream>>>(x, W, ei, xb, Wbf, bhist,
                                                nNodes, nEdges, nB, nHB);
    bucket_scan_kernel<<<1, 1024, 0, stream>>>(bhist, boff, bcur, nB, nEdges);
    partition_kernel<<<nHB, 1024, 0, stream>>>(ei, bcur, packed, nEdges, nB);
    bucket_gather_gemm_kernel<<<nB, 128, 0, stream>>>(
        (const uint*)xb, packed, boff, Wbf, b, out, nNodes);
  } else {
    hipMemsetAsync(d_out, 0, (size_t)out_size * sizeof(float), stream);
    scatter_add_kernel<<<(nEdges + 3) / 4, 256, 0, stream>>>(x, ei, out, nEdges);
    linear_relu_inplace_kernel<<<(nNodes + 3) / 4, 256, 0, stream>>>(out, W, b, nNodes);
  }
}